// Round 2
// baseline (2883.796 us; speedup 1.0000x reference)
//
#include <hip/hip_runtime.h>
#include <hip/hip_bf16.h>
#include <math.h>

// NTM forward, fully fused: one block per batch element, T=64 steps in-kernel.
// M[1024][64] fp32 lives in registers: 512 threads x 2 rows x 64 floats.
// Input/output dtype is detected at runtime (w_bias sums to 1.0 iff the
// buffers really are bf16); both template instantiations launch, one no-ops.

constexpr int kB  = 64;
constexpr int kT  = 64;
constexpr int kIN = 64;
constexpr int kC  = 256;
constexpr int kN  = 1024;
constexpr int kMV = 64;
constexpr int kOUT = 64;
constexpr int kHW = 198;   // write head raw dim: MV+6+2*MV
constexpr int kHR = 70;    // read head raw dim: MV+6
constexpr int NT  = 512;   // threads per block (8 waves)
constexpr float kEPS = 1e-8f;

__device__ __forceinline__ float ldf(const float* p, int i) { return p[i]; }
__device__ __forceinline__ float ldf(const __hip_bfloat16* p, int i) { return __bfloat162float(p[i]); }
__device__ __forceinline__ void stf(float* p, int i, float v) { p[i] = v; }
__device__ __forceinline__ void stf(__hip_bfloat16* p, int i, float v) { p[i] = __float2bfloat16(v); }

__device__ __forceinline__ float sigmoidf_(float v) { return 1.f / (1.f + expf(-v)); }
__device__ __forceinline__ float softplusf_(float v) { return v > 20.f ? v : log1pf(expf(v)); }

__device__ __forceinline__ float wsum(float v) {
  v += __shfl_xor(v, 32); v += __shfl_xor(v, 16); v += __shfl_xor(v, 8);
  v += __shfl_xor(v, 4);  v += __shfl_xor(v, 2);  v += __shfl_xor(v, 1);
  return v;
}
__device__ __forceinline__ float wmax(float v) {
  v = fmaxf(v, __shfl_xor(v, 32)); v = fmaxf(v, __shfl_xor(v, 16));
  v = fmaxf(v, __shfl_xor(v, 8));  v = fmaxf(v, __shfl_xor(v, 4));
  v = fmaxf(v, __shfl_xor(v, 2));  v = fmaxf(v, __shfl_xor(v, 1));
  return v;
}

struct Smem {
  float in[kIN + kMV];      // controller input concat(x_t, r)
  float c[kC];              // controller activations
  float h[kHW];             // write head raw
  float hr[kHR];            // read head raw
  float k[kMV], kr[kMV], e[kMV], a[kMV], r[kMV];
  float part[8][kC];        // GEMM partials
  float wg[kN];             // interpolated weights (for circular shift)
  float red[3][8];          // cross-wave reduction slots
  float scal[16];           // 0..6 write head: beta,g,gamma,s0,s1,s2,|k| ; 8..14 read head
  float tmp[NT][17];        // read-vector column reduction (pad 17 -> conflict-free)
};

__device__ __forceinline__ void address2(Smem& sm, int tid, int lane, int wid,
                                         float sim0, float sim1,
                                         float g, float s0, float s1, float s2, float gamma,
                                         float wp0, float wp1,
                                         float& w0, float& w1) {
  float m = wmax(fmaxf(sim0, sim1));
  if (lane == 0) sm.red[0][wid] = m;
  __syncthreads();
  float gmax = sm.red[0][0];
  #pragma unroll
  for (int i = 1; i < NT / 64; ++i) gmax = fmaxf(gmax, sm.red[0][i]);
  float e0 = expf(sim0 - gmax), e1 = expf(sim1 - gmax);
  float sv = wsum(e0 + e1);
  if (lane == 0) sm.red[1][wid] = sv;
  __syncthreads();
  float gsum = 0.f;
  #pragma unroll
  for (int i = 0; i < NT / 64; ++i) gsum += sm.red[1][i];
  float inv = 1.f / gsum;
  float wg0 = fmaf(g, fmaf(e0, inv, -wp0), wp0);
  float wg1 = fmaf(g, fmaf(e1, inv, -wp1), wp1);
  sm.wg[tid] = wg0; sm.wg[tid + NT] = wg1;
  __syncthreads();
  // circular conv: s[0]*w[n+1] + s[1]*w[n] + s[2]*w[n-1]  (SHIFTS = -1,0,+1)
  float ws0 = s0 * sm.wg[(tid + 1) & (kN - 1)] + s1 * wg0 + s2 * sm.wg[(tid + kN - 1) & (kN - 1)];
  float ws1 = s0 * sm.wg[(tid + NT + 1) & (kN - 1)] + s1 * wg1 + s2 * sm.wg[(tid + NT - 1) & (kN - 1)];
  float p0 = expf(gamma * logf(ws0 + kEPS));
  float p1 = expf(gamma * logf(ws1 + kEPS));
  float pv = wsum(p0 + p1);
  if (lane == 0) sm.red[2][wid] = pv;
  __syncthreads();
  float psum = 0.f;
  #pragma unroll
  for (int i = 0; i < NT / 64; ++i) psum += sm.red[2][i];
  float ipn = 1.f / psum;
  w0 = p0 * ipn; w1 = p1 * ipn;
}

// flag: 1 if buffers are bf16, 0 if fp32.  w_bias is a softmax -> sums to 1.
__global__ void detect_dtype(const void* wb, int* flag) {
  if (threadIdx.x == 0 && blockIdx.x == 0) {
    const unsigned short* u = (const unsigned short*)wb;
    float s = 0.f;
    for (int i = 0; i < kN; ++i) {
      float v = __uint_as_float(((unsigned int)u[i]) << 16);
      s += v;
    }
    // bf16 story: s ~= 1.  fp32 story: even elements are fp32 mantissa bits
    // read as bf16 (random exponent) -> |s| huge or NaN -> comparison false.
    *flag = (s > 0.75f && s < 1.25f) ? 1 : 0;
  }
}

template <typename TD, int WANT>
__global__ __launch_bounds__(NT, 2) void ntm_fused(
    const TD* __restrict__ x,
    const TD* __restrict__ Wc, const TD* __restrict__ bc,
    const TD* __restrict__ Wr, const TD* __restrict__ br,
    const TD* __restrict__ Ww, const TD* __restrict__ bw,
    const TD* __restrict__ Wf, const TD* __restrict__ bf,
    const TD* __restrict__ r_bias, const TD* __restrict__ w_bias,
    const TD* __restrict__ M_bias,
    TD* __restrict__ out, const int* __restrict__ flag) {
  if (*flag != WANT) return;
  __shared__ Smem sm;
  const int tid  = threadIdx.x;
  const int b    = blockIdx.x;
  const int lane = tid & 63;
  const int wid  = tid >> 6;

  // ---- init state: M rows (registers), row norms, prev weights, read vector
  float M0[kMV], M1[kMV];
  float n2_0 = 0.f, n2_1 = 0.f;
  #pragma unroll
  for (int j = 0; j < kMV; ++j) {
    M0[j] = ldf(M_bias, tid * kMV + j);
    M1[j] = ldf(M_bias, (tid + NT) * kMV + j);
    n2_0 = fmaf(M0[j], M0[j], n2_0);
    n2_1 = fmaf(M1[j], M1[j], n2_1);
  }
  float wp0 = ldf(w_bias, tid);
  float wp1 = ldf(w_bias, tid + NT);
  if (tid < kMV) sm.r[tid] = ldf(r_bias, tid);
  __syncthreads();

  #pragma unroll 1
  for (int t = 0; t < kT; ++t) {
    // ---- stage controller input [x_t, r]
    if (tid < kIN) sm.in[tid] = ldf(x, (b * kT + t) * kIN + tid);
    else if (tid < kIN + kMV) sm.in[tid] = sm.r[tid - kIN];
    __syncthreads();

    // ---- controller: c = tanh(in @ Wc + bc)   (256 outs, 128 in; 2 partials)
    {
      const int j = tid & 255, p = tid >> 8;
      float s = 0.f;
      #pragma unroll 8
      for (int i = 0; i < 64; ++i)
        s = fmaf(sm.in[p * 64 + i], ldf(Wc, (p * 64 + i) * kC + j), s);
      sm.part[p][j] = s;
    }
    __syncthreads();
    if (tid < kC) sm.c[tid] = tanhf(sm.part[0][tid] + sm.part[1][tid] + ldf(bc, tid));
    __syncthreads();

    // ---- head GEMMs: hw = c @ Ww + bw (198), hr = c @ Wr + br (70)
    {
      const int j = tid & 255, p = tid >> 8;
      if (j < kHW) {
        float s = 0.f;
        #pragma unroll 8
        for (int i = 0; i < 128; ++i)
          s = fmaf(sm.c[p * 128 + i], ldf(Ww, (p * 128 + i) * kHW + j), s);
        sm.part[p][j] = s;
      }
      if (j < kHR) {
        float s = 0.f;
        #pragma unroll 8
        for (int i = 0; i < 128; ++i)
          s = fmaf(sm.c[p * 128 + i], ldf(Wr, (p * 128 + i) * kHR + j), s);
        sm.part[2 + p][j] = s;
      }
    }
    __syncthreads();
    if (tid < kHW) sm.h[tid] = sm.part[0][tid] + sm.part[1][tid] + ldf(bw, tid);
    if (tid >= 256 && tid < 256 + kHR) {
      int j = tid - 256;
      sm.hr[j] = sm.part[2][j] + sm.part[3][j] + ldf(br, j);
    }
    __syncthreads();

    // ---- head params (wave-uniform branches)
    if (wid == 0) {                       // write key + |k|
      float kv = tanhf(sm.h[lane]); sm.k[lane] = kv;
      float s = wsum(kv * kv);
      if (lane == 0) sm.scal[6] = sqrtf(s);
    } else if (wid == 1) {                // erase
      sm.e[lane] = sigmoidf_(sm.h[70 + lane]);
    } else if (wid == 2) {                // add
      sm.a[lane] = tanhf(sm.h[134 + lane]);
    } else if (wid == 3) {                // read key + |k|
      float kv = tanhf(sm.hr[lane]); sm.kr[lane] = kv;
      float s = wsum(kv * kv);
      if (lane == 0) sm.scal[14] = sqrtf(s);
    } else if (tid == 256) {              // write head scalars
      sm.scal[0] = softplusf_(sm.h[64]);
      sm.scal[1] = sigmoidf_(sm.h[65]);
      sm.scal[2] = 1.f + softplusf_(sm.h[69]);
      float a0 = sm.h[66], a1 = sm.h[67], a2 = sm.h[68];
      float mx = fmaxf(a0, fmaxf(a1, a2));
      float e0 = expf(a0 - mx), e1 = expf(a1 - mx), e2 = expf(a2 - mx);
      float d = 1.f / (e0 + e1 + e2);
      sm.scal[3] = e0 * d; sm.scal[4] = e1 * d; sm.scal[5] = e2 * d;
    } else if (tid == 320) {              // read head scalars
      sm.scal[8]  = softplusf_(sm.hr[64]);
      sm.scal[9]  = sigmoidf_(sm.hr[65]);
      sm.scal[10] = 1.f + softplusf_(sm.hr[69]);
      float a0 = sm.hr[66], a1 = sm.hr[67], a2 = sm.hr[68];
      float mx = fmaxf(a0, fmaxf(a1, a2));
      float e0 = expf(a0 - mx), e1 = expf(a1 - mx), e2 = expf(a2 - mx);
      float d = 1.f / (e0 + e1 + e2);
      sm.scal[11] = e0 * d; sm.scal[12] = e1 * d; sm.scal[13] = e2 * d;
    }
    __syncthreads();

    // ---- write head addressing
    float ww0, ww1;
    {
      float beta = sm.scal[0], g = sm.scal[1], gamma = sm.scal[2];
      float s0 = sm.scal[3], s1 = sm.scal[4], s2 = sm.scal[5], kn = sm.scal[6];
      float d0 = 0.f, d1 = 0.f;
      #pragma unroll
      for (int j = 0; j < kMV; ++j) {
        float kv = sm.k[j];
        d0 = fmaf(M0[j], kv, d0);
        d1 = fmaf(M1[j], kv, d1);
      }
      float sim0 = beta * d0 / (sqrtf(n2_0) * kn + kEPS);
      float sim1 = beta * d1 / (sqrtf(n2_1) * kn + kEPS);
      address2(sm, tid, lane, wid, sim0, sim1, g, s0, s1, s2, gamma, wp0, wp1, ww0, ww1);
    }

    // ---- memory update, fused with read-head dot + new row norm
    float dr0 = 0.f, dr1 = 0.f, nn0 = 0.f, nn1 = 0.f;
    #pragma unroll
    for (int j = 0; j < kMV; ++j) {
      float ev = sm.e[j], av = sm.a[j], kv = sm.kr[j];
      float m0 = fmaf(ww0, fmaf(-ev, M0[j], av), M0[j]);  // M*(1-w e) + w a
      float m1 = fmaf(ww1, fmaf(-ev, M1[j], av), M1[j]);
      M0[j] = m0; M1[j] = m1;
      dr0 = fmaf(m0, kv, dr0); nn0 = fmaf(m0, m0, nn0);
      dr1 = fmaf(m1, kv, dr1); nn1 = fmaf(m1, m1, nn1);
    }

    // ---- read head addressing (prev weights = write weights)
    float wr0, wr1;
    {
      float beta = sm.scal[8], g = sm.scal[9], gamma = sm.scal[10];
      float s0 = sm.scal[11], s1 = sm.scal[12], s2 = sm.scal[13], kn = sm.scal[14];
      float sim0 = beta * dr0 / (sqrtf(nn0) * kn + kEPS);
      float sim1 = beta * dr1 / (sqrtf(nn1) * kn + kEPS);
      address2(sm, tid, lane, wid, sim0, sim1, g, s0, s1, s2, gamma, ww0, ww1, wr0, wr1);
    }
    wp0 = wr0; wp1 = wr1; n2_0 = nn0; n2_1 = nn1;   // carry state

    // ---- read vector r[j] = sum_n w_r[n] M[n][j]  (chunked column reduce)
    #pragma unroll
    for (int cb = 0; cb < kMV; cb += 16) {
      #pragma unroll
      for (int u = 0; u < 16; ++u)
        sm.tmp[tid][u] = fmaf(wr0, M0[cb + u], wr1 * M1[cb + u]);
      __syncthreads();
      {
        int u2 = tid >> 5, i2 = tid & 31;   // 32 threads per column
        float s = 0.f;
        #pragma unroll
        for (int q = 0; q < 16; ++q) s += sm.tmp[i2 + 32 * q][u2];
        s += __shfl_xor(s, 16); s += __shfl_xor(s, 8);
        s += __shfl_xor(s, 4);  s += __shfl_xor(s, 2); s += __shfl_xor(s, 1);
        if (i2 == 0) sm.r[cb + u2] = s;
      }
      __syncthreads();
    }

    // ---- output: sigmoid([c, r] @ Wf + bf)  (64 outs, 320 in; 8 partials of 40)
    {
      const int j = tid & 63, p = tid >> 6;
      float s = 0.f;
      #pragma unroll
      for (int i = 0; i < 40; ++i) {
        int idx = p * 40 + i;
        float v = (idx < kC) ? sm.c[idx] : sm.r[idx - kC];
        s = fmaf(v, ldf(Wf, idx * kOUT + j), s);
      }
      sm.part[p][j] = s;
    }
    __syncthreads();
    if (tid < kOUT) {
      float s = ldf(bf, tid);
      #pragma unroll
      for (int p = 0; p < 8; ++p) s += sm.part[p][tid];
      stf(out, (b * kT + t) * kOUT + tid, sigmoidf_(s));
    }
    __syncthreads();
  }
}

template <typename TD, int WANT>
static void launch_variant(void* const* d_in, void* d_out, const int* flag, hipStream_t stream) {
  ntm_fused<TD, WANT><<<dim3(kB), dim3(NT), 0, stream>>>(
      (const TD*)d_in[0], (const TD*)d_in[1], (const TD*)d_in[2],
      (const TD*)d_in[3], (const TD*)d_in[4], (const TD*)d_in[5],
      (const TD*)d_in[6], (const TD*)d_in[7], (const TD*)d_in[8],
      (const TD*)d_in[9], (const TD*)d_in[10], (const TD*)d_in[11],
      (TD*)d_out, flag);
}

extern "C" void kernel_launch(void* const* d_in, const int* in_sizes, int n_in,
                              void* d_out, int out_size, void* d_ws, size_t ws_size,
                              hipStream_t stream) {
  (void)in_sizes; (void)n_in; (void)ws_size; (void)out_size;
  int* flag = (int*)d_ws;
  detect_dtype<<<dim3(1), dim3(64), 0, stream>>>(d_in[10], flag);
  launch_variant<__hip_bfloat16, 1>(d_in, d_out, flag, stream);
  launch_variant<float, 0>(d_in, d_out, flag, stream);
}